// Round 13
// baseline (262782.422 us; speedup 1.0000x reference)
//
#include <hip/hip_runtime.h>
#include <math.h>

#define H 1024
#define D 256
#define NB 64        // 64 blocks: 16 units/layer each
#define NT 512
#define LW 64        // warmup (teacher-forced) length

typedef float f32x4 __attribute__((ext_vector_type(4)));

__device__ __forceinline__ float sigf(float v) { return 1.f / (1.f + __expf(-v)); }

__device__ __forceinline__ float waveReduce(float v) {
#pragma unroll
    for (int off = 32; off > 0; off >>= 1) v += __shfl_xor(v, off, 64);
    return v;
}

// LLC-coherent ops (sc0 sc1 bypass L1/L2).
__device__ __forceinline__ f32x4 ldg4_nw(const float* p) {   // issue only
    f32x4 r;
    asm volatile("global_load_dwordx4 %0, %1, off sc0 sc1" : "=v"(r) : "v"(p) : "memory");
    return r;
}
__device__ __forceinline__ void vm_wait1(f32x4& a) {         // data-chained wait (rule-18 safe)
    asm volatile("s_waitcnt vmcnt(0)" : "+v"(a) :: "memory");
    __builtin_amdgcn_sched_barrier(0);
}
__device__ __forceinline__ void stg4_sc(float* p, f32x4 v) {
    asm volatile("global_store_dwordx4 %0, %1, off sc0 sc1" :: "v"(p), "v"(v) : "memory");
}

// Tags: |value| < 1 always; producer stores value + tag, tag = 8*(s&3)-12 in
// {-12,-4,4,12}. Valid iff |x - tag| < 2. Zero / 0xAA / stale (tag distance
// >= 8) can never false-validate. Skew bound < 2 steps < period 4 (each block
// passes 4 gather gates per step, so no producer can lap a consumer).
__device__ __forceinline__ float tagf(int i) { return 8.0f * (float)(i & 3) - 12.0f; }
__device__ __forceinline__ bool vld4(f32x4 c, float tg) {
    float m = fmaxf(fmaxf(fabsf(c.x - tg), fabsf(c.y - tg)),
                    fmaxf(fabsf(c.z - tg), fabsf(c.w - tg)));
    return m < 2.0f;
}

// ---- static exchange buffers ----
// [0 .. 256)                  inp chunks: block b at b*4 (4 floats)
// [256 + (l*2+p)*1024 .. )    hg[layer l][ping-pong p]: block b at b*16 (64B line)
#define EXN (256 + 6 * 1024)
__device__ float g_ex[EXN];

__global__ void ws_clear() {
    int i = blockIdx.x * blockDim.x + threadIdx.x;
    for (; i < EXN; i += gridDim.x * blockDim.x) g_ex[i] = 0.f;
}

__global__ __launch_bounds__(NT, 2) void rnn_reg10(
    const float* __restrict__ x, const float* __restrict__ h0in, const float* __restrict__ c0,
    const float* __restrict__ Wih0, const float* __restrict__ Whh0,
    const float* __restrict__ Wih1, const float* __restrict__ Whh1,
    const float* __restrict__ Wih2, const float* __restrict__ Whh2,
    const float* __restrict__ b_ih, const float* __restrict__ b_hh,
    const float* __restrict__ Wfc, const float* __restrict__ bfc,
    float* __restrict__ out, int T, int L)
{
    const int b = blockIdx.x;
    const int tid = threadIdx.x;
    const int w = tid >> 6;
    const int lane = tid & 63;
    const int g = w & 3;            // gate i,f,g,o
    const int uh = w >> 2;          // unit-half: 0..1 (8 units each)
    const int off = lane * 4;

    float* inpw = g_ex;

    __shared__ __align__(16) float lds_h0[H], lds_h1[H], lds_h2[H];
    __shared__ __align__(16) float lds_inp[D];
    __shared__ __align__(16) float lds_fc[4 * H];
    __shared__ float lds_x[4 * LW];
    __shared__ float lds_bias[3 * 64];   // [layer][unit*4+gate] for this block's 16 units
    __shared__ float lds_bfc[4];
    __shared__ float gate_buf[64];       // [unit*4+gate]
    __shared__ float red[4];
    __shared__ float c_st[48];           // [layer*16+unit]

    // ---- one-time: weights -> registers (8 rows/wave, 168 VGPR) ----
    float4 w0[8][5], w1[8][8], w2[8][8];
#pragma unroll
    for (int i = 0; i < 8; ++i) {
        const int r = g * H + b * 16 + uh * 8 + i;
        w0[i][0] = *(const float4*)(Wih0 + (size_t)r * 256 + off);
#pragma unroll
        for (int j = 0; j < 4; ++j) {
            w0[i][1 + j] = *(const float4*)(Whh0 + (size_t)r * H + j * 256 + off);
            w1[i][j]     = *(const float4*)(Wih1 + (size_t)r * H + j * 256 + off);
            w1[i][4 + j] = *(const float4*)(Whh1 + (size_t)r * H + j * 256 + off);
            w2[i][j]     = *(const float4*)(Wih2 + (size_t)r * H + j * 256 + off);
            w2[i][4 + j] = *(const float4*)(Whh2 + (size_t)r * H + j * 256 + off);
        }
    }
#define KA(v) asm volatile("" : "+v"(v.x), "+v"(v.y), "+v"(v.z), "+v"(v.w))
#pragma unroll
    for (int i = 0; i < 8; ++i) {
#pragma unroll
        for (int j = 0; j < 5; ++j) KA(w0[i][j]);
#pragma unroll
        for (int j = 0; j < 8; ++j) { KA(w1[i][j]); KA(w2[i][j]); }
    }
#undef KA

    // ---- prologue: LDS fills ----
    for (int i = tid; i < H; i += NT) {
        lds_h0[i] = h0in[i];
        lds_h1[i] = h0in[H + i];
        lds_h2[i] = h0in[2 * H + i];
    }
    for (int i = tid; i < 4 * H; i += NT) lds_fc[i] = Wfc[(size_t)(4 * b) * H + i];
    if (tid < 4 * LW) {
        int j = tid >> 6, t = tid & 63;
        if (t < L) lds_x[j * LW + t] = x[(size_t)(4 * b + j) * L + t];
    }
    if (tid < 192) {
        int l = tid >> 6, e = tid & 63, u = e >> 2, gg = e & 3;
        int idx = l * 4 * H + gg * H + b * 16 + u;
        lds_bias[tid] = b_ih[idx] + b_hh[idx];
    }
    if (tid < 48) c_st[tid] = c0[(tid >> 4) * H + b * 16 + (tid & 15)];
    if (tid < 4) lds_bfc[tid] = bfc[4 * b + tid];
    __syncthreads();
    if (tid == 0) {
        float n0 = lds_x[0], n1 = lds_x[LW], n2 = lds_x[2 * LW], n3 = lds_x[3 * LW];
        out[(size_t)(4 * b + 0) * T] = n0;
        out[(size_t)(4 * b + 1) * T] = n1;
        out[(size_t)(4 * b + 2) * T] = n2;
        out[(size_t)(4 * b + 3) * T] = n3;
        lds_inp[b * 4 + 0] = n0; lds_inp[b * 4 + 1] = n1;
        lds_inp[b * 4 + 2] = n2; lds_inp[b * 4 + 3] = n3;
        float tg = tagf(0);
        f32x4 pk = {n0 + tg, n1 + tg, n2 + tg, n3 + tg};
        stg4_sc(inpw + b * 4, pk);
    }

#define FMA4(A, W, V) { A.x += (W).x*(V).x; A.y += (W).y*(V).y; A.z += (W).z*(V).z; A.w += (W).w*(V).w; }

#define DOT(WARR, N1, P1, N2, P2)                                              \
    {                                                                          \
        f32x4 ac0={0,0,0,0},ac1={0,0,0,0},ac2={0,0,0,0},ac3={0,0,0,0};         \
        f32x4 ac4={0,0,0,0},ac5={0,0,0,0},ac6={0,0,0,0},ac7={0,0,0,0};         \
        _Pragma("unroll")                                                      \
        for (int j = 0; j < N1; ++j) {                                         \
            f32x4 v = *(const f32x4*)((P1) + j * 256 + off);                   \
            FMA4(ac0, WARR[0][j], v) FMA4(ac1, WARR[1][j], v)                  \
            FMA4(ac2, WARR[2][j], v) FMA4(ac3, WARR[3][j], v)                  \
            FMA4(ac4, WARR[4][j], v) FMA4(ac5, WARR[5][j], v)                  \
            FMA4(ac6, WARR[6][j], v) FMA4(ac7, WARR[7][j], v)                  \
        }                                                                      \
        _Pragma("unroll")                                                      \
        for (int j = 0; j < N2; ++j) {                                         \
            f32x4 v = *(const f32x4*)((P2) + j * 256 + off);                   \
            FMA4(ac0, WARR[0][N1+j], v) FMA4(ac1, WARR[1][N1+j], v)            \
            FMA4(ac2, WARR[2][N1+j], v) FMA4(ac3, WARR[3][N1+j], v)            \
            FMA4(ac4, WARR[4][N1+j], v) FMA4(ac5, WARR[5][N1+j], v)            \
            FMA4(ac6, WARR[6][N1+j], v) FMA4(ac7, WARR[7][N1+j], v)            \
        }                                                                      \
        float r0_ = waveReduce(ac0.x + ac0.y + ac0.z + ac0.w);                 \
        float r1_ = waveReduce(ac1.x + ac1.y + ac1.z + ac1.w);                 \
        float r2_ = waveReduce(ac2.x + ac2.y + ac2.z + ac2.w);                 \
        float r3_ = waveReduce(ac3.x + ac3.y + ac3.z + ac3.w);                 \
        float r4_ = waveReduce(ac4.x + ac4.y + ac4.z + ac4.w);                 \
        float r5_ = waveReduce(ac5.x + ac5.y + ac5.z + ac5.w);                 \
        float r6_ = waveReduce(ac6.x + ac6.y + ac6.z + ac6.w);                 \
        float r7_ = waveReduce(ac7.x + ac7.y + ac7.z + ac7.w);                 \
        if (lane == 0) {                                                      \
            gate_buf[(uh*8+0)*4+g]=r0_; gate_buf[(uh*8+1)*4+g]=r1_;            \
            gate_buf[(uh*8+2)*4+g]=r2_; gate_buf[(uh*8+3)*4+g]=r3_;            \
            gate_buf[(uh*8+4)*4+g]=r4_; gate_buf[(uh*8+5)*4+g]=r5_;            \
            gate_buf[(uh*8+6)*4+g]=r6_; gate_buf[(uh*8+7)*4+g]=r7_;            \
        }                                                                      \
    }

    // wave 7: combine all 16 units; 4 tagged 16B stores (one 64B line) + LDS mirror.
#define COMBINE(LIDX, HGPTR, TG, LDSH)                                         \
    if (w == 7) {                                                              \
        int u = lane >> 2;                                                     \
        float val = gate_buf[lane] + lds_bias[(LIDX) * 64 + lane];             \
        int qb = lane & ~3;                                                    \
        float gi = __shfl(val, qb + 0), gf = __shfl(val, qb + 1);              \
        float gG = __shfl(val, qb + 2), go = __shfl(val, qb + 3);              \
        float cn = sigf(gf) * c_st[(LIDX) * 16 + u] + sigf(gi) * tanhf(gG);    \
        float hn = sigf(go) * tanhf(cn);                                       \
        if ((lane & 3) == 0) {                                                 \
            c_st[(LIDX) * 16 + u] = cn;                                        \
            (LDSH)[b * 16 + u] = hn;                                           \
        }                                                                      \
        float p0 = __shfl(hn, (lane & 3) * 16 + 0);                            \
        float p1 = __shfl(hn, (lane & 3) * 16 + 4);                            \
        float p2 = __shfl(hn, (lane & 3) * 16 + 8);                            \
        float p3 = __shfl(hn, (lane & 3) * 16 + 12);                           \
        if (lane < 4) {                                                        \
            f32x4 pk = {p0 + (TG), p1 + (TG), p2 + (TG), p3 + (TG)};           \
            stg4_sc((HGPTR) + b * 16 + lane * 4, pk);                          \
        }                                                                      \
    }

    // waves 0-3 poll the 256 16B quarters (1/lane); self chunk via LDS mirror.
#define POLLH(SRC, DST, TG)                                                    \
    if (w < 4) {                                                               \
        const int q = w * 64 + lane;                                           \
        const float* s_ = (SRC) + q * 4;                                       \
        float* d_ = (DST) + q * 4;                                             \
        const float tg_ = (TG);                                                \
        bool done = ((q >> 2) == b);                                           \
        int spin = 0;                                                          \
        for (;;) {                                                             \
            f32x4 v = {0, 0, 0, 0};                                            \
            if (!done) v = ldg4_nw(s_);                                        \
            vm_wait1(v);                                                       \
            if (!done && vld4(v, tg_)) {                                       \
                f32x4 u = {v.x - tg_, v.y - tg_, v.z - tg_, v.w - tg_};        \
                *(f32x4*)d_ = u;                                               \
                done = true;                                                   \
            }                                                                  \
            if (__all(done)) break;                                            \
            if (++spin > 2) __builtin_amdgcn_s_sleep(8);                       \
            else            __builtin_amdgcn_s_sleep(1);                       \
        }                                                                      \
    }

    for (int s = 0; s < T - 1; ++s) {
        const int ps = s & 1;
        const float tagS = tagf(s);
        float* hg0 = g_ex + 256 + (0 * 2 + ps) * 1024;
        float* hg1 = g_ex + 256 + (1 * 2 + ps) * 1024;
        float* hg2 = g_ex + 256 + (2 * 2 + ps) * 1024;

        // ---------- phase A: gather inp (wave 0, 1 chunk/lane), layer 0 ----------
        if (w == 0) {
            bool done = (lane == b);
            int spin = 0;
            for (;;) {
                f32x4 v = {0, 0, 0, 0};
                if (!done) v = ldg4_nw(inpw + lane * 4);
                vm_wait1(v);
                if (!done && vld4(v, tagS)) {
                    f32x4 u = {v.x - tagS, v.y - tagS, v.z - tagS, v.w - tagS};
                    *(f32x4*)(lds_inp + lane * 4) = u;
                    done = true;
                }
                if (__all(done)) break;
                if (++spin > 2) __builtin_amdgcn_s_sleep(8);
                else            __builtin_amdgcn_s_sleep(1);
            }
        }
        __syncthreads();
        DOT(w0, 1, lds_inp, 4, lds_h0)
        __syncthreads();
        COMBINE(0, hg0, tagS, lds_h0)

        // ---------- phase B: gather h0_new -> lds_h0 (dual use), layer 1 ----------
        POLLH(hg0, lds_h0, tagS)
        __syncthreads();
        DOT(w1, 4, lds_h0, 4, lds_h1)
        __syncthreads();
        COMBINE(1, hg1, tagS, lds_h1)

        // ---------- phase C: gather h1_new -> lds_h1, layer 2 ----------
        POLLH(hg1, lds_h1, tagS)
        __syncthreads();
        DOT(w2, 4, lds_h1, 4, lds_h2)
        __syncthreads();
        COMBINE(2, hg2, tagS, lds_h2)

        // ---------- phase D: gather h2_new -> lds_h2, distributed fc ----------
        POLLH(hg2, lds_h2, tagS)
        __syncthreads();
        if (w < 4) {
            const float* fr = lds_fc + w * H;
            f32x4 a = {0, 0, 0, 0};
#pragma unroll
            for (int k = 0; k < 4; ++k) {
                f32x4 hv = *(const f32x4*)(lds_h2 + lane * 16 + k * 4);
                f32x4 fv = *(const f32x4*)(fr + lane * 16 + k * 4);
                FMA4(a, fv, hv)
            }
            float sres = waveReduce(a.x + a.y + a.z + a.w);
            if (lane == 0) red[w] = sres + lds_bfc[w];
        }
        __syncthreads();
        if (tid == 0) {
            const int sp1 = s + 1;
            float n0, n1, n2, n3;
            if (sp1 < L) {
                n0 = lds_x[sp1]; n1 = lds_x[LW + sp1];
                n2 = lds_x[2 * LW + sp1]; n3 = lds_x[3 * LW + sp1];
            } else {
                n0 = sigf(red[0]); n1 = sigf(red[1]);
                n2 = sigf(red[2]); n3 = sigf(red[3]);
            }
            out[(size_t)(4 * b + 0) * T + sp1] = n0;
            out[(size_t)(4 * b + 1) * T + sp1] = n1;
            out[(size_t)(4 * b + 2) * T + sp1] = n2;
            out[(size_t)(4 * b + 3) * T + sp1] = n3;
            lds_inp[b * 4 + 0] = n0; lds_inp[b * 4 + 1] = n1;
            lds_inp[b * 4 + 2] = n2; lds_inp[b * 4 + 3] = n3;
            float tg = tagf(sp1);
            f32x4 pk = {n0 + tg, n1 + tg, n2 + tg, n3 + tg};
            stg4_sc(inpw + b * 4, pk);
        }
    }
#undef DOT
#undef COMBINE
#undef POLLH
#undef FMA4
}

extern "C" void kernel_launch(void* const* d_in, const int* in_sizes, int n_in,
                              void* d_out, int out_size, void* d_ws, size_t ws_size,
                              hipStream_t stream) {
    const float* x    = (const float*)d_in[0];
    const float* h0   = (const float*)d_in[1];
    const float* c0   = (const float*)d_in[2];
    const float* Wih0 = (const float*)d_in[3];
    const float* Whh0 = (const float*)d_in[4];
    const float* Wih1 = (const float*)d_in[5];
    const float* Whh1 = (const float*)d_in[6];
    const float* Wih2 = (const float*)d_in[7];
    const float* Whh2 = (const float*)d_in[8];
    const float* bih  = (const float*)d_in[9];
    const float* bhh  = (const float*)d_in[10];
    const float* Wfc  = (const float*)d_in[11];
    const float* bfc  = (const float*)d_in[12];

    float* out = (float*)d_out;

    int T = out_size / D;        // 2048
    int L = in_sizes[0] / D;     // 64

    ws_clear<<<13, 512, 0, stream>>>();

    void* args[] = { &x, &h0, &c0, &Wih0, &Whh0, &Wih1, &Whh1, &Wih2, &Whh2,
                     &bih, &bhh, &Wfc, &bfc, &out, &T, &L };

    (void)hipLaunchCooperativeKernel((void*)rnn_reg10, dim3(NB), dim3(NT), args, 0, stream);
}